// Round 5
// baseline (120.742 us; speedup 1.0000x reference)
//
#include <hip/hip_runtime.h>
#include <math.h>

// Problem constants: B=2, L=256, D=256, H=4, DH=64.
// Output tuple: out (B,L,D)=131072 floats, then attn (B,H,L,L)=524288 floats.
//
// Algebra:
//  - qh . (pitch_rel @ pr_w^T)  ==  pitch_rel . (qh @ pr_w_headslice)  -> precompute qpr.
//  - pr_b / dr_b are j-constant logit offsets -> cancel in softmax -> dropped.
//  - 1/sqrt(DH) folded into qh.
//  - k_bias v4: persistent streaming. One block per (b,i) (512 blocks = exactly
//    2 blocks/CU), wave w owns j in [w*64, w*64+64), 8 groups of 8 j, double-
//    buffered register prefetch (16 float4 in flight while computing), qk/mask
//    preloaded to registers, nontemporal loads (no reuse -> bypass L2 churn),
//    LDS-transpose reduce in per-wave region (no block barrier).

typedef float nfloat4 __attribute__((ext_vector_type(4)));

static __device__ __forceinline__ float4 ntload4(const float4* p) {
  nfloat4 r = __builtin_nontemporal_load((const nfloat4*)p);
  return make_float4(r.x, r.y, r.z, r.w);
}

// ---------------------------------------------------------------- A0: transpose fc_w
__global__ __launch_bounds__(256) void k_transpose(const float* __restrict__ in,
                                                   float* __restrict__ out) {
  __shared__ float t[32][33];
  int bx = blockIdx.x & 7, by = blockIdx.x >> 3;
  int x = threadIdx.x & 31, y0 = threadIdx.x >> 5;
#pragma unroll
  for (int yy = 0; yy < 32; yy += 8)
    t[yy + y0][x] = in[(size_t)(by * 32 + yy + y0) * 256 + bx * 32 + x];
  __syncthreads();
#pragma unroll
  for (int yy = 0; yy < 32; yy += 8)
    out[(size_t)(bx * 32 + yy + y0) * 256 + by * 32 + x] = t[x][yy + y0];
}

// ---------------------------------------------------------------- A1: q/k/v projections
__global__ __launch_bounds__(256) void k_proj(
    const float* __restrict__ q, const float* __restrict__ k_, const float* __restrict__ v,
    const float* __restrict__ Wq, const float* __restrict__ Bq,
    const float* __restrict__ Wk, const float* __restrict__ Bk,
    const float* __restrict__ Wv, const float* __restrict__ Bv,
    float* __restrict__ qh, float* __restrict__ kh, float* __restrict__ vh) {
  int blk = blockIdx.x;
  int m = blk >> 5;
  int r = blk & 31;
  int b = r >> 4, it = (r >> 2) & 3, ot = r & 3;
  const float* X = (m == 0) ? q : (m == 1) ? k_ : v;
  const float* W = (m == 0) ? Wq : (m == 1) ? Wk : Wv;
  const float* Bs = (m == 0) ? Bq : (m == 1) ? Bk : Bv;
  float* OUT = (m == 0) ? qh : (m == 1) ? kh : vh;
  const float scale = (m == 0) ? 0.125f : 1.0f;

  __shared__ float xs[64][33];
  __shared__ float ws[64][33];
  int tid = threadIdx.x;
  int ti = tid >> 4, to = tid & 15;
  int lr = tid >> 2, lc = (tid & 3) * 8;
  float acc[4][4] = {};

  for (int k0 = 0; k0 < 256; k0 += 32) {
    float4 a0 = *(const float4*)(X + (size_t)(b * 256 + it * 64 + lr) * 256 + k0 + lc);
    float4 a1 = *(const float4*)(X + (size_t)(b * 256 + it * 64 + lr) * 256 + k0 + lc + 4);
    xs[lr][lc + 0] = a0.x; xs[lr][lc + 1] = a0.y; xs[lr][lc + 2] = a0.z; xs[lr][lc + 3] = a0.w;
    xs[lr][lc + 4] = a1.x; xs[lr][lc + 5] = a1.y; xs[lr][lc + 6] = a1.z; xs[lr][lc + 7] = a1.w;
    float4 w0 = *(const float4*)(W + (size_t)(ot * 64 + lr) * 256 + k0 + lc);
    float4 w1 = *(const float4*)(W + (size_t)(ot * 64 + lr) * 256 + k0 + lc + 4);
    ws[lr][lc + 0] = w0.x; ws[lr][lc + 1] = w0.y; ws[lr][lc + 2] = w0.z; ws[lr][lc + 3] = w0.w;
    ws[lr][lc + 4] = w1.x; ws[lr][lc + 5] = w1.y; ws[lr][lc + 6] = w1.z; ws[lr][lc + 7] = w1.w;
    __syncthreads();
#pragma unroll
    for (int kk = 0; kk < 32; ++kk) {
      float xv0 = xs[ti * 4 + 0][kk], xv1 = xs[ti * 4 + 1][kk];
      float xv2 = xs[ti * 4 + 2][kk], xv3 = xs[ti * 4 + 3][kk];
      float wv0 = ws[0 * 16 + to][kk], wv1 = ws[1 * 16 + to][kk];
      float wv2 = ws[2 * 16 + to][kk], wv3 = ws[3 * 16 + to][kk];
      acc[0][0] += xv0 * wv0; acc[0][1] += xv0 * wv1; acc[0][2] += xv0 * wv2; acc[0][3] += xv0 * wv3;
      acc[1][0] += xv1 * wv0; acc[1][1] += xv1 * wv1; acc[1][2] += xv1 * wv2; acc[1][3] += xv1 * wv3;
      acc[2][0] += xv2 * wv0; acc[2][1] += xv2 * wv1; acc[2][2] += xv2 * wv2; acc[2][3] += xv2 * wv3;
      acc[3][0] += xv3 * wv0; acc[3][1] += xv3 * wv1; acc[3][2] += xv3 * wv2; acc[3][3] += xv3 * wv3;
    }
    __syncthreads();
  }
#pragma unroll
  for (int ii = 0; ii < 4; ++ii)
#pragma unroll
    for (int oo = 0; oo < 4; ++oo) {
      int i = it * 64 + ti * 4 + ii;
      int dd = oo * 16 + to;
      OUT[(size_t)((b * 4 + ot) * 256 + i) * 64 + dd] = (acc[ii][oo] + Bs[ot * 64 + dd]) * scale;
    }
}

// ---------------------------------------------------------------- A2: qpr / qdr
__global__ __launch_bounds__(256) void k_qprdr(
    const float* __restrict__ qh, const float* __restrict__ prw,
    const float* __restrict__ drw, float* __restrict__ qpr, float* __restrict__ qdr) {
  int blk = blockIdx.x;  // t*128 + rt*4 + et
  int t = blk >> 7;
  int r2 = blk & 127;
  int rt = r2 >> 2, et = r2 & 3;
  const float* W = t ? drw : prw;
  float* OUT = t ? qdr : qpr;
  int h = (rt >> 2) & 3;

  __shared__ float xs[64][33];
  __shared__ float ws2[32][64];
  int tid = threadIdx.x;
  int ti = tid >> 4, to = tid & 15;
  float acc[4][4] = {};

  for (int k0 = 0; k0 < 64; k0 += 32) {
    int lr = tid >> 2, lc = (tid & 3) * 8;
    float4 a0 = *(const float4*)(qh + (size_t)(rt * 64 + lr) * 64 + k0 + lc);
    float4 a1 = *(const float4*)(qh + (size_t)(rt * 64 + lr) * 64 + k0 + lc + 4);
    xs[lr][lc + 0] = a0.x; xs[lr][lc + 1] = a0.y; xs[lr][lc + 2] = a0.z; xs[lr][lc + 3] = a0.w;
    xs[lr][lc + 4] = a1.x; xs[lr][lc + 5] = a1.y; xs[lr][lc + 6] = a1.z; xs[lr][lc + 7] = a1.w;
    int wr = tid >> 3, wc = (tid & 7) * 8;
    float4 w0 = *(const float4*)(W + (size_t)(h * 64 + k0 + wr) * 256 + et * 64 + wc);
    float4 w1 = *(const float4*)(W + (size_t)(h * 64 + k0 + wr) * 256 + et * 64 + wc + 4);
    ws2[wr][wc + 0] = w0.x; ws2[wr][wc + 1] = w0.y; ws2[wr][wc + 2] = w0.z; ws2[wr][wc + 3] = w0.w;
    ws2[wr][wc + 4] = w1.x; ws2[wr][wc + 5] = w1.y; ws2[wr][wc + 6] = w1.z; ws2[wr][wc + 7] = w1.w;
    __syncthreads();
#pragma unroll
    for (int kk = 0; kk < 32; ++kk) {
      float xv0 = xs[ti * 4 + 0][kk], xv1 = xs[ti * 4 + 1][kk];
      float xv2 = xs[ti * 4 + 2][kk], xv3 = xs[ti * 4 + 3][kk];
      float wv0 = ws2[kk][0 * 16 + to], wv1 = ws2[kk][1 * 16 + to];
      float wv2 = ws2[kk][2 * 16 + to], wv3 = ws2[kk][3 * 16 + to];
      acc[0][0] += xv0 * wv0; acc[0][1] += xv0 * wv1; acc[0][2] += xv0 * wv2; acc[0][3] += xv0 * wv3;
      acc[1][0] += xv1 * wv0; acc[1][1] += xv1 * wv1; acc[1][2] += xv1 * wv2; acc[1][3] += xv1 * wv3;
      acc[2][0] += xv2 * wv0; acc[2][1] += xv2 * wv1; acc[2][2] += xv2 * wv2; acc[2][3] += xv2 * wv3;
      acc[3][0] += xv3 * wv0; acc[3][1] += xv3 * wv1; acc[3][2] += xv3 * wv2; acc[3][3] += xv3 * wv3;
    }
    __syncthreads();
  }
#pragma unroll
  for (int ii = 0; ii < 4; ++ii)
#pragma unroll
    for (int oo = 0; oo < 4; ++oo)
      OUT[(size_t)(rt * 64 + ti * 4 + ii) * 256 + et * 64 + oo * 16 + to] = acc[ii][oo];
}

// ---------------------------------------------------------------- A3: content logits qk
__global__ __launch_bounds__(256) void k_qk(const float* __restrict__ qh,
                                            const float* __restrict__ kh,
                                            float* __restrict__ qk) {
  int blk = blockIdx.x;  // bh*16 + it*4 + jt
  int bh = blk >> 4, it = (blk >> 2) & 3, jt = blk & 3;
  __shared__ float xs[64][33];
  __shared__ float ys[64][33];
  int tid = threadIdx.x;
  int ti = tid >> 4, to = tid & 15;
  float acc[4][4] = {};

  for (int k0 = 0; k0 < 64; k0 += 32) {
    int lr = tid >> 2, lc = (tid & 3) * 8;
    float4 a0 = *(const float4*)(qh + (size_t)(bh * 256 + it * 64 + lr) * 64 + k0 + lc);
    float4 a1 = *(const float4*)(qh + (size_t)(bh * 256 + it * 64 + lr) * 64 + k0 + lc + 4);
    xs[lr][lc + 0] = a0.x; xs[lr][lc + 1] = a0.y; xs[lr][lc + 2] = a0.z; xs[lr][lc + 3] = a0.w;
    xs[lr][lc + 4] = a1.x; xs[lr][lc + 5] = a1.y; xs[lr][lc + 6] = a1.z; xs[lr][lc + 7] = a1.w;
    float4 b0 = *(const float4*)(kh + (size_t)(bh * 256 + jt * 64 + lr) * 64 + k0 + lc);
    float4 b1 = *(const float4*)(kh + (size_t)(bh * 256 + jt * 64 + lr) * 64 + k0 + lc + 4);
    ys[lr][lc + 0] = b0.x; ys[lr][lc + 1] = b0.y; ys[lr][lc + 2] = b0.z; ys[lr][lc + 3] = b0.w;
    ys[lr][lc + 4] = b1.x; ys[lr][lc + 5] = b1.y; ys[lr][lc + 6] = b1.z; ys[lr][lc + 7] = b1.w;
    __syncthreads();
#pragma unroll
    for (int kk = 0; kk < 32; ++kk) {
      float xv0 = xs[ti * 4 + 0][kk], xv1 = xs[ti * 4 + 1][kk];
      float xv2 = xs[ti * 4 + 2][kk], xv3 = xs[ti * 4 + 3][kk];
      float wv0 = ys[0 * 16 + to][kk], wv1 = ys[1 * 16 + to][kk];
      float wv2 = ys[2 * 16 + to][kk], wv3 = ys[3 * 16 + to][kk];
      acc[0][0] += xv0 * wv0; acc[0][1] += xv0 * wv1; acc[0][2] += xv0 * wv2; acc[0][3] += xv0 * wv3;
      acc[1][0] += xv1 * wv0; acc[1][1] += xv1 * wv1; acc[1][2] += xv1 * wv2; acc[1][3] += xv1 * wv3;
      acc[2][0] += xv2 * wv0; acc[2][1] += xv2 * wv1; acc[2][2] += xv2 * wv2; acc[2][3] += xv2 * wv3;
      acc[3][0] += xv3 * wv0; acc[3][1] += xv3 * wv1; acc[3][2] += xv3 * wv2; acc[3][3] += xv3 * wv3;
    }
    __syncthreads();
  }
#pragma unroll
  for (int ii = 0; ii < 4; ++ii)
#pragma unroll
    for (int jj = 0; jj < 4; ++jj)
      qk[(size_t)(bh * 256 + it * 64 + ti * 4 + ii) * 256 + jt * 64 + jj * 16 + to] = acc[ii][jj];
}

// ---------------------------------------------------------------- B1: bias stream (HOT, v4)
// One block per (b,i); wave w owns j in [w*64, w*64+64), 8 groups of 8 j.
// Double-buffered register prefetch; 16-32 float4 loads in flight sustained.
__global__ __launch_bounds__(256, 2) void k_bias(
    const float* __restrict__ pitch, const float* __restrict__ dur,
    const float* __restrict__ qpr, const float* __restrict__ qdr,
    const float* __restrict__ amask, const unsigned char* __restrict__ kpm,
    float* __restrict__ attn) {
  int bi = blockIdx.x;  // b*256 + i
  int b = bi >> 8, i = bi & 255;
  int tid = threadIdx.x, w = tid >> 6, l = tid & 63;
  int jbase = w * 64;

  __shared__ float red[4][8][4][65];  // per-wave regions, no block barrier

  // qp/qd fragments (e-slice 4l..4l+3) for all 4 heads
  float4 qp[4], qd[4];
#pragma unroll
  for (int h = 0; h < 4; ++h) {
    qp[h] = *(const float4*)(qpr + (size_t)((b * 4 + h) * 256 + i) * 256 + 4 * l);
    qd[h] = *(const float4*)(qdr + (size_t)((b * 4 + h) * 256 + i) * 256 + 4 * l);
  }

  // epilogue assignment: p = l&31 -> (jj_o, h_o); lane handles j = jbase + g*8 + jj_o
  int p = l & 31;
  int jj_o = p >> 2, h_o = p & 3;
  size_t orow0 = (size_t)((b * 4 + h_o) * 256 + i) * 256 + jbase + jj_o;
  bool rowm = kpm[b * 256 + i] != 0;
  float qk8[8];
  int mbits = 0;
#pragma unroll
  for (int g = 0; g < 8; ++g) {
    qk8[g] = attn[orow0 + 8 * g];
    if (rowm || amask[(size_t)i * 256 + jbase + g * 8 + jj_o] != 0.f) mbits |= (1 << g);
  }

  const float4* prow =
      (const float4*)(pitch + (size_t)(b * 256 + i) * 65536) + (size_t)jbase * 64 + l;
  const float4* drow =
      (const float4*)(dur + (size_t)(b * 256 + i) * 65536) + (size_t)jbase * 64 + l;

  float4 Pa[8], Da[8], Pb[8], Db[8];

#define LOADG(PB, DB, g)                                  \
  {                                                       \
    _Pragma("unroll") for (int t = 0; t < 8; ++t) {       \
      PB[t] = ntload4(prow + ((g) * 8 + t) * 64);         \
      DB[t] = ntload4(drow + ((g) * 8 + t) * 64);         \
    }                                                     \
  }

#define CSTORE(PB, DB, g)                                                       \
  {                                                                             \
    _Pragma("unroll") for (int t = 0; t < 8; ++t) {                             \
      _Pragma("unroll") for (int h = 0; h < 4; ++h) {                           \
        red[w][t][h][l] =                                                       \
            PB[t].x * qp[h].x + PB[t].y * qp[h].y + PB[t].z * qp[h].z +         \
            PB[t].w * qp[h].w + DB[t].x * qd[h].x + DB[t].y * qd[h].y +         \
            DB[t].z * qd[h].z + DB[t].w * qd[h].w;                              \
      }                                                                         \
    }                                                                           \
    float x = 0.f;                                                              \
    {                                                                           \
      const float* rr = &red[w][jj_o][h_o][(l >> 5) * 32];                      \
      _Pragma("unroll 8") for (int c = 0; c < 32; ++c) x += rr[c];              \
    }                                                                           \
    x += __shfl_xor(x, 32);                                                     \
    if (l < 32) {                                                               \
      float val = qk8[g] + x;                                                   \
      if (mbits & (1 << (g))) val = -9e15f;                                     \
      attn[orow0 + 8 * (g)] = val;                                              \
    }                                                                           \
  }

  LOADG(Pa, Da, 0);
#pragma unroll
  for (int gg = 0; gg < 4; ++gg) {
    LOADG(Pb, Db, 2 * gg + 1);
    CSTORE(Pa, Da, 2 * gg);
    if (gg < 3) LOADG(Pa, Da, 2 * gg + 2);
    CSTORE(Pb, Db, 2 * gg + 1);
  }
#undef LOADG
#undef CSTORE
}

// ---------------------------------------------------------------- B2: softmax + PV + fc
__global__ __launch_bounds__(256) void k_pv_fc(
    float* __restrict__ attn, const float* __restrict__ vh,
    const float* __restrict__ fcT, const float* __restrict__ fcb,
    float* __restrict__ out) {
  int b = blockIdx.x >> 8, i = blockIdx.x & 255;
  int tid = threadIdx.x;
  int h = tid >> 6, l = tid & 63;

  __shared__ float arow[4][256];
  __shared__ float pre[256];

  // fused softmax: wave h owns row (b,h,i)
  float* rowp = attn + (size_t)((b * 4 + h) * 256 + i) * 256;
  float4 v4 = *(float4*)(rowp + 4 * l);
  float mx = fmaxf(fmaxf(v4.x, v4.y), fmaxf(v4.z, v4.w));
#pragma unroll
  for (int m = 1; m <= 32; m <<= 1) mx = fmaxf(mx, __shfl_xor(mx, m));
  float e0 = __expf(v4.x - mx), e1 = __expf(v4.y - mx);
  float e2 = __expf(v4.z - mx), e3 = __expf(v4.w - mx);
  float sm = e0 + e1 + e2 + e3;
#pragma unroll
  for (int m = 1; m <= 32; m <<= 1) sm += __shfl_xor(sm, m);
  float inv = 1.0f / sm;
  float4 a4 = make_float4(e0 * inv, e1 * inv, e2 * inv, e3 * inv);
  *(float4*)(rowp + 4 * l) = a4;
  *(float4*)&arow[h][4 * l] = a4;
  __syncthreads();

  float acc = 0.f;
  const float* vbase = vh + (size_t)(b * 4 + h) * 256 * 64 + l;
#pragma unroll 4
  for (int jj = 0; jj < 256; ++jj) acc += arow[h][jj] * vbase[(size_t)jj * 64];
  pre[tid] = acc;
  __syncthreads();

  float acc2 = fcb[tid];
#pragma unroll 4
  for (int c = 0; c < 256; ++c) acc2 += pre[c] * fcT[(size_t)c * 256 + tid];
  out[(size_t)(b * 256 + i) * 256 + tid] = acc2;
}

// ---------------------------------------------------------------- launcher
extern "C" void kernel_launch(void* const* d_in, const int* in_sizes, int n_in,
                              void* d_out, int out_size, void* d_ws, size_t ws_size,
                              hipStream_t stream) {
  (void)in_sizes; (void)n_in; (void)out_size; (void)ws_size;
  const float* q = (const float*)d_in[0];
  const float* k = (const float*)d_in[1];
  const float* v = (const float*)d_in[2];
  const float* amask = (const float*)d_in[3];
  const unsigned char* kpm = (const unsigned char*)d_in[4];
  const float* pitch = (const float*)d_in[5];
  const float* dur = (const float*)d_in[6];
  const float* Wq = (const float*)d_in[7];
  const float* Bq = (const float*)d_in[8];
  const float* Wk = (const float*)d_in[9];
  const float* Bk = (const float*)d_in[10];
  const float* Wv = (const float*)d_in[11];
  const float* Bv = (const float*)d_in[12];
  const float* fcw = (const float*)d_in[13];
  const float* fcb = (const float*)d_in[14];
  const float* prw = (const float*)d_in[15];
  const float* drw = (const float*)d_in[17];
  // pr_b (16) / dr_b (18) intentionally unused: j-constant logit offsets cancel in softmax.

  float* out = (float*)d_out;
  float* attn = out + 2 * 256 * 256;  // 131072

  float* wsf = (float*)d_ws;
  float* qh = wsf;              // 131072
  float* kh = qh + 131072;      // 131072
  float* vh = kh + 131072;      // 131072
  float* qpr = vh + 131072;     // 524288
  float* qdr = qpr + 524288;    // 524288
  float* fcT = qdr + 524288;    // 65536   (total ~6.03 MB)

  k_transpose<<<64, 256, 0, stream>>>(fcw, fcT);
  k_proj<<<96, 256, 0, stream>>>(q, k, v, Wq, Bq, Wk, Bk, Wv, Bv, qh, kh, vh);
  k_qprdr<<<256, 256, 0, stream>>>(qh, prw, drw, qpr, qdr);
  k_qk<<<128, 256, 0, stream>>>(qh, kh, attn);
  k_bias<<<512, 256, 0, stream>>>(pitch, dur, qpr, qdr, amask, kpm, attn);
  k_pv_fc<<<512, 256, 0, stream>>>(attn, vh, fcT, fcb, out);
}

// Round 6
// 116.554 us; speedup vs baseline: 1.0359x; 1.0359x over previous
//
#include <hip/hip_runtime.h>
#include <math.h>

// Problem constants: B=2, L=256, D=256, H=4, DH=64.
// Output tuple: out (B,L,D)=131072 floats, then attn (B,H,L,L)=524288 floats.
//
// Algebra:
//  - qh . (pitch_rel @ pr_w^T)  ==  pitch_rel . (qh @ pr_w_headslice)  -> precompute qpr.
//  - pr_b / dr_b are j-constant logit offsets -> cancel in softmax -> dropped.
//  - 1/sqrt(DH) folded into qh.
//  - k_fused: whole B-phase in one kernel. One block per (b,i): stream
//    pitch/dur rows (512 KB) with double-buffered register prefetch, masked
//    logits into LDS, softmax per head (write attn), PV against L2-resident
//    vh, fc against L2-resident fcT. No inter-kernel attn round trip.

typedef float nfloat4 __attribute__((ext_vector_type(4)));

static __device__ __forceinline__ float4 ntload4(const float4* p) {
  nfloat4 r = __builtin_nontemporal_load((const nfloat4*)p);
  return make_float4(r.x, r.y, r.z, r.w);
}

// ---------------------------------------------------------------- A0: transpose fc_w
__global__ __launch_bounds__(256) void k_transpose(const float* __restrict__ in,
                                                   float* __restrict__ out) {
  __shared__ float t[32][33];
  int bx = blockIdx.x & 7, by = blockIdx.x >> 3;
  int x = threadIdx.x & 31, y0 = threadIdx.x >> 5;
#pragma unroll
  for (int yy = 0; yy < 32; yy += 8)
    t[yy + y0][x] = in[(size_t)(by * 32 + yy + y0) * 256 + bx * 32 + x];
  __syncthreads();
#pragma unroll
  for (int yy = 0; yy < 32; yy += 8)
    out[(size_t)(bx * 32 + yy + y0) * 256 + by * 32 + x] = t[x][yy + y0];
}

// ---------------------------------------------------------------- A1: q/k/v projections
__global__ __launch_bounds__(256) void k_proj(
    const float* __restrict__ q, const float* __restrict__ k_, const float* __restrict__ v,
    const float* __restrict__ Wq, const float* __restrict__ Bq,
    const float* __restrict__ Wk, const float* __restrict__ Bk,
    const float* __restrict__ Wv, const float* __restrict__ Bv,
    float* __restrict__ qh, float* __restrict__ kh, float* __restrict__ vh) {
  int blk = blockIdx.x;
  int m = blk >> 5;
  int r = blk & 31;
  int b = r >> 4, it = (r >> 2) & 3, ot = r & 3;
  const float* X = (m == 0) ? q : (m == 1) ? k_ : v;
  const float* W = (m == 0) ? Wq : (m == 1) ? Wk : Wv;
  const float* Bs = (m == 0) ? Bq : (m == 1) ? Bk : Bv;
  float* OUT = (m == 0) ? qh : (m == 1) ? kh : vh;
  const float scale = (m == 0) ? 0.125f : 1.0f;

  __shared__ float xs[64][33];
  __shared__ float ws[64][33];
  int tid = threadIdx.x;
  int ti = tid >> 4, to = tid & 15;
  int lr = tid >> 2, lc = (tid & 3) * 8;
  float acc[4][4] = {};

  for (int k0 = 0; k0 < 256; k0 += 32) {
    float4 a0 = *(const float4*)(X + (size_t)(b * 256 + it * 64 + lr) * 256 + k0 + lc);
    float4 a1 = *(const float4*)(X + (size_t)(b * 256 + it * 64 + lr) * 256 + k0 + lc + 4);
    xs[lr][lc + 0] = a0.x; xs[lr][lc + 1] = a0.y; xs[lr][lc + 2] = a0.z; xs[lr][lc + 3] = a0.w;
    xs[lr][lc + 4] = a1.x; xs[lr][lc + 5] = a1.y; xs[lr][lc + 6] = a1.z; xs[lr][lc + 7] = a1.w;
    float4 w0 = *(const float4*)(W + (size_t)(ot * 64 + lr) * 256 + k0 + lc);
    float4 w1 = *(const float4*)(W + (size_t)(ot * 64 + lr) * 256 + k0 + lc + 4);
    ws[lr][lc + 0] = w0.x; ws[lr][lc + 1] = w0.y; ws[lr][lc + 2] = w0.z; ws[lr][lc + 3] = w0.w;
    ws[lr][lc + 4] = w1.x; ws[lr][lc + 5] = w1.y; ws[lr][lc + 6] = w1.z; ws[lr][lc + 7] = w1.w;
    __syncthreads();
#pragma unroll
    for (int kk = 0; kk < 32; ++kk) {
      float xv0 = xs[ti * 4 + 0][kk], xv1 = xs[ti * 4 + 1][kk];
      float xv2 = xs[ti * 4 + 2][kk], xv3 = xs[ti * 4 + 3][kk];
      float wv0 = ws[0 * 16 + to][kk], wv1 = ws[1 * 16 + to][kk];
      float wv2 = ws[2 * 16 + to][kk], wv3 = ws[3 * 16 + to][kk];
      acc[0][0] += xv0 * wv0; acc[0][1] += xv0 * wv1; acc[0][2] += xv0 * wv2; acc[0][3] += xv0 * wv3;
      acc[1][0] += xv1 * wv0; acc[1][1] += xv1 * wv1; acc[1][2] += xv1 * wv2; acc[1][3] += xv1 * wv3;
      acc[2][0] += xv2 * wv0; acc[2][1] += xv2 * wv1; acc[2][2] += xv2 * wv2; acc[2][3] += xv2 * wv3;
      acc[3][0] += xv3 * wv0; acc[3][1] += xv3 * wv1; acc[3][2] += xv3 * wv2; acc[3][3] += xv3 * wv3;
    }
    __syncthreads();
  }
#pragma unroll
  for (int ii = 0; ii < 4; ++ii)
#pragma unroll
    for (int oo = 0; oo < 4; ++oo) {
      int i = it * 64 + ti * 4 + ii;
      int dd = oo * 16 + to;
      OUT[(size_t)((b * 4 + ot) * 256 + i) * 64 + dd] = (acc[ii][oo] + Bs[ot * 64 + dd]) * scale;
    }
}

// ---------------------------------------------------------------- A2: qpr / qdr
__global__ __launch_bounds__(256) void k_qprdr(
    const float* __restrict__ qh, const float* __restrict__ prw,
    const float* __restrict__ drw, float* __restrict__ qpr, float* __restrict__ qdr) {
  int blk = blockIdx.x;  // t*128 + rt*4 + et
  int t = blk >> 7;
  int r2 = blk & 127;
  int rt = r2 >> 2, et = r2 & 3;
  const float* W = t ? drw : prw;
  float* OUT = t ? qdr : qpr;
  int h = (rt >> 2) & 3;

  __shared__ float xs[64][33];
  __shared__ float ws2[32][64];
  int tid = threadIdx.x;
  int ti = tid >> 4, to = tid & 15;
  float acc[4][4] = {};

  for (int k0 = 0; k0 < 64; k0 += 32) {
    int lr = tid >> 2, lc = (tid & 3) * 8;
    float4 a0 = *(const float4*)(qh + (size_t)(rt * 64 + lr) * 64 + k0 + lc);
    float4 a1 = *(const float4*)(qh + (size_t)(rt * 64 + lr) * 64 + k0 + lc + 4);
    xs[lr][lc + 0] = a0.x; xs[lr][lc + 1] = a0.y; xs[lr][lc + 2] = a0.z; xs[lr][lc + 3] = a0.w;
    xs[lr][lc + 4] = a1.x; xs[lr][lc + 5] = a1.y; xs[lr][lc + 6] = a1.z; xs[lr][lc + 7] = a1.w;
    int wr = tid >> 3, wc = (tid & 7) * 8;
    float4 w0 = *(const float4*)(W + (size_t)(h * 64 + k0 + wr) * 256 + et * 64 + wc);
    float4 w1 = *(const float4*)(W + (size_t)(h * 64 + k0 + wr) * 256 + et * 64 + wc + 4);
    ws2[wr][wc + 0] = w0.x; ws2[wr][wc + 1] = w0.y; ws2[wr][wc + 2] = w0.z; ws2[wr][wc + 3] = w0.w;
    ws2[wr][wc + 4] = w1.x; ws2[wr][wc + 5] = w1.y; ws2[wr][wc + 6] = w1.z; ws2[wr][wc + 7] = w1.w;
    __syncthreads();
#pragma unroll
    for (int kk = 0; kk < 32; ++kk) {
      float xv0 = xs[ti * 4 + 0][kk], xv1 = xs[ti * 4 + 1][kk];
      float xv2 = xs[ti * 4 + 2][kk], xv3 = xs[ti * 4 + 3][kk];
      float wv0 = ws2[kk][0 * 16 + to], wv1 = ws2[kk][1 * 16 + to];
      float wv2 = ws2[kk][2 * 16 + to], wv3 = ws2[kk][3 * 16 + to];
      acc[0][0] += xv0 * wv0; acc[0][1] += xv0 * wv1; acc[0][2] += xv0 * wv2; acc[0][3] += xv0 * wv3;
      acc[1][0] += xv1 * wv0; acc[1][1] += xv1 * wv1; acc[1][2] += xv1 * wv2; acc[1][3] += xv1 * wv3;
      acc[2][0] += xv2 * wv0; acc[2][1] += xv2 * wv1; acc[2][2] += xv2 * wv2; acc[2][3] += xv2 * wv3;
      acc[3][0] += xv3 * wv0; acc[3][1] += xv3 * wv1; acc[3][2] += xv3 * wv2; acc[3][3] += xv3 * wv3;
    }
    __syncthreads();
  }
#pragma unroll
  for (int ii = 0; ii < 4; ++ii)
#pragma unroll
    for (int oo = 0; oo < 4; ++oo)
      OUT[(size_t)(rt * 64 + ti * 4 + ii) * 256 + et * 64 + oo * 16 + to] = acc[ii][oo];
}

// ---------------------------------------------------------------- A3: content logits qk
__global__ __launch_bounds__(256) void k_qk(const float* __restrict__ qh,
                                            const float* __restrict__ kh,
                                            float* __restrict__ qk) {
  int blk = blockIdx.x;  // bh*16 + it*4 + jt
  int bh = blk >> 4, it = (blk >> 2) & 3, jt = blk & 3;
  __shared__ float xs[64][33];
  __shared__ float ys[64][33];
  int tid = threadIdx.x;
  int ti = tid >> 4, to = tid & 15;
  float acc[4][4] = {};

  for (int k0 = 0; k0 < 64; k0 += 32) {
    int lr = tid >> 2, lc = (tid & 3) * 8;
    float4 a0 = *(const float4*)(qh + (size_t)(bh * 256 + it * 64 + lr) * 64 + k0 + lc);
    float4 a1 = *(const float4*)(qh + (size_t)(bh * 256 + it * 64 + lr) * 64 + k0 + lc + 4);
    xs[lr][lc + 0] = a0.x; xs[lr][lc + 1] = a0.y; xs[lr][lc + 2] = a0.z; xs[lr][lc + 3] = a0.w;
    xs[lr][lc + 4] = a1.x; xs[lr][lc + 5] = a1.y; xs[lr][lc + 6] = a1.z; xs[lr][lc + 7] = a1.w;
    float4 b0 = *(const float4*)(kh + (size_t)(bh * 256 + jt * 64 + lr) * 64 + k0 + lc);
    float4 b1 = *(const float4*)(kh + (size_t)(bh * 256 + jt * 64 + lr) * 64 + k0 + lc + 4);
    ys[lr][lc + 0] = b0.x; ys[lr][lc + 1] = b0.y; ys[lr][lc + 2] = b0.z; ys[lr][lc + 3] = b0.w;
    ys[lr][lc + 4] = b1.x; ys[lr][lc + 5] = b1.y; ys[lr][lc + 6] = b1.z; ys[lr][lc + 7] = b1.w;
    __syncthreads();
#pragma unroll
    for (int kk = 0; kk < 32; ++kk) {
      float xv0 = xs[ti * 4 + 0][kk], xv1 = xs[ti * 4 + 1][kk];
      float xv2 = xs[ti * 4 + 2][kk], xv3 = xs[ti * 4 + 3][kk];
      float wv0 = ys[0 * 16 + to][kk], wv1 = ys[1 * 16 + to][kk];
      float wv2 = ys[2 * 16 + to][kk], wv3 = ys[3 * 16 + to][kk];
      acc[0][0] += xv0 * wv0; acc[0][1] += xv0 * wv1; acc[0][2] += xv0 * wv2; acc[0][3] += xv0 * wv3;
      acc[1][0] += xv1 * wv0; acc[1][1] += xv1 * wv1; acc[1][2] += xv1 * wv2; acc[1][3] += xv1 * wv3;
      acc[2][0] += xv2 * wv0; acc[2][1] += xv2 * wv1; acc[2][2] += xv2 * wv2; acc[2][3] += xv2 * wv3;
      acc[3][0] += xv3 * wv0; acc[3][1] += xv3 * wv1; acc[3][2] += xv3 * wv2; acc[3][3] += xv3 * wv3;
    }
    __syncthreads();
  }
#pragma unroll
  for (int ii = 0; ii < 4; ++ii)
#pragma unroll
    for (int jj = 0; jj < 4; ++jj)
      qk[(size_t)(bh * 256 + it * 64 + ti * 4 + ii) * 256 + jt * 64 + jj * 16 + to] = acc[ii][jj];
}

// ---------------------------------------------------------------- B: fused bias+softmax+PV+fc
// One block per (b,i). Wave w owns j in [w*64, w*64+64) for the bias stream,
// then head h=w for softmax/PV. Masked logits accumulate in LDS; attn written
// once; PV uses L2-resident vh; fc uses L2-resident fcT.
__global__ __launch_bounds__(256, 2) void k_fused(
    const float* __restrict__ pitch, const float* __restrict__ dur,
    const float* __restrict__ qpr, const float* __restrict__ qdr,
    const float* __restrict__ amask, const unsigned char* __restrict__ kpm,
    const float* __restrict__ vh, const float* __restrict__ fcT,
    const float* __restrict__ fcb, float* __restrict__ attn,
    float* __restrict__ out) {
  int bi = blockIdx.x;  // b*256 + i
  int b = bi >> 8, i = bi & 255;
  int tid = threadIdx.x, w = tid >> 6, l = tid & 63;
  int jbase = w * 64;

  __shared__ float red[4][8][4][65];   // 33.3 KB, per-wave regions
  __shared__ float logits[4][264];     // padded: h*264+j -> conflict-free scatter
  __shared__ float pre[256];

  // qp/qd fragments (e-slice 4l..4l+3) for all 4 heads
  float4 qp[4], qd[4];
#pragma unroll
  for (int h = 0; h < 4; ++h) {
    qp[h] = *(const float4*)(qpr + (size_t)((b * 4 + h) * 256 + i) * 256 + 4 * l);
    qd[h] = *(const float4*)(qdr + (size_t)((b * 4 + h) * 256 + i) * 256 + 4 * l);
  }

  // output assignment for the reduce: p = l&31 -> (jj_o, h_o)
  int p = l & 31;
  int jj_o = p >> 2, h_o = p & 3;
  size_t qrow0 = (size_t)((b * 4 + h_o) * 256 + i) * 256 + jbase + jj_o;
  bool rowm = kpm[b * 256 + i] != 0;
  float qk8[8];
  int mbits = 0;
#pragma unroll
  for (int g = 0; g < 8; ++g) {
    qk8[g] = attn[qrow0 + 8 * g];
    if (rowm || amask[(size_t)i * 256 + jbase + g * 8 + jj_o] != 0.f) mbits |= (1 << g);
  }

  const float4* prow =
      (const float4*)(pitch + (size_t)(b * 256 + i) * 65536) + (size_t)jbase * 64 + l;
  const float4* drow =
      (const float4*)(dur + (size_t)(b * 256 + i) * 65536) + (size_t)jbase * 64 + l;

  float4 Pa[8], Da[8], Pb[8], Db[8];

#define LOADG(PB, DB, g)                                  \
  {                                                       \
    _Pragma("unroll") for (int t = 0; t < 8; ++t) {       \
      PB[t] = ntload4(prow + ((g) * 8 + t) * 64);         \
      DB[t] = ntload4(drow + ((g) * 8 + t) * 64);         \
    }                                                     \
  }

#define CSTORE(PB, DB, g)                                                       \
  {                                                                             \
    _Pragma("unroll") for (int t = 0; t < 8; ++t) {                             \
      _Pragma("unroll") for (int h = 0; h < 4; ++h) {                           \
        red[w][t][h][l] =                                                       \
            PB[t].x * qp[h].x + PB[t].y * qp[h].y + PB[t].z * qp[h].z +         \
            PB[t].w * qp[h].w + DB[t].x * qd[h].x + DB[t].y * qd[h].y +         \
            DB[t].z * qd[h].z + DB[t].w * qd[h].w;                              \
      }                                                                         \
    }                                                                           \
    float x = 0.f;                                                              \
    {                                                                           \
      const float* rr = &red[w][jj_o][h_o][(l >> 5) * 32];                      \
      _Pragma("unroll 8") for (int c = 0; c < 32; ++c) x += rr[c];              \
    }                                                                           \
    x += __shfl_xor(x, 32);                                                     \
    if (l < 32) {                                                               \
      float val = qk8[g] + x;                                                   \
      if (mbits & (1 << (g))) val = -9e15f;                                     \
      logits[h_o][jbase + (g) * 8 + jj_o] = val;                                \
    }                                                                           \
  }

  LOADG(Pa, Da, 0);
#pragma unroll
  for (int gg = 0; gg < 4; ++gg) {
    LOADG(Pb, Db, 2 * gg + 1);
    CSTORE(Pa, Da, 2 * gg);
    if (gg < 3) LOADG(Pa, Da, 2 * gg + 2);
    CSTORE(Pb, Db, 2 * gg + 1);
  }
#undef LOADG
#undef CSTORE
  __syncthreads();

  // ---- softmax: wave w owns head w; lane l handles j = 4l..4l+3
  float* lrow = &logits[w][0];
  float4 v4 = *(float4*)(lrow + 4 * l);
  float mx = fmaxf(fmaxf(v4.x, v4.y), fmaxf(v4.z, v4.w));
#pragma unroll
  for (int m = 1; m <= 32; m <<= 1) mx = fmaxf(mx, __shfl_xor(mx, m));
  float e0 = __expf(v4.x - mx), e1 = __expf(v4.y - mx);
  float e2 = __expf(v4.z - mx), e3 = __expf(v4.w - mx);
  float sm = e0 + e1 + e2 + e3;
#pragma unroll
  for (int m = 1; m <= 32; m <<= 1) sm += __shfl_xor(sm, m);
  float inv = 1.0f / sm;
  float4 a4 = make_float4(e0 * inv, e1 * inv, e2 * inv, e3 * inv);
  *(float4*)(lrow + 4 * l) = a4;
  *(float4*)(attn + (size_t)((b * 4 + w) * 256 + i) * 256 + 4 * l) = a4;
  __syncthreads();

  // ---- PV: thread (h=w, l): out-dim l of head w
  float acc = 0.f;
  const float* vbase = vh + (size_t)(b * 4 + w) * 256 * 64 + l;
#pragma unroll 4
  for (int jj = 0; jj < 256; ++jj) acc += lrow[jj] * vbase[(size_t)jj * 64];
  pre[tid] = acc;
  __syncthreads();

  // ---- fc
  float acc2 = fcb[tid];
#pragma unroll 4
  for (int c = 0; c < 256; ++c) acc2 += pre[c] * fcT[(size_t)c * 256 + tid];
  out[(size_t)(b * 256 + i) * 256 + tid] = acc2;
}

// ---------------------------------------------------------------- launcher
extern "C" void kernel_launch(void* const* d_in, const int* in_sizes, int n_in,
                              void* d_out, int out_size, void* d_ws, size_t ws_size,
                              hipStream_t stream) {
  (void)in_sizes; (void)n_in; (void)out_size; (void)ws_size;
  const float* q = (const float*)d_in[0];
  const float* k = (const float*)d_in[1];
  const float* v = (const float*)d_in[2];
  const float* amask = (const float*)d_in[3];
  const unsigned char* kpm = (const unsigned char*)d_in[4];
  const float* pitch = (const float*)d_in[5];
  const float* dur = (const float*)d_in[6];
  const float* Wq = (const float*)d_in[7];
  const float* Bq = (const float*)d_in[8];
  const float* Wk = (const float*)d_in[9];
  const float* Bk = (const float*)d_in[10];
  const float* Wv = (const float*)d_in[11];
  const float* Bv = (const float*)d_in[12];
  const float* fcw = (const float*)d_in[13];
  const float* fcb = (const float*)d_in[14];
  const float* prw = (const float*)d_in[15];
  const float* drw = (const float*)d_in[17];
  // pr_b (16) / dr_b (18) intentionally unused: j-constant logit offsets cancel in softmax.

  float* out = (float*)d_out;
  float* attn = out + 2 * 256 * 256;  // 131072

  float* wsf = (float*)d_ws;
  float* qh = wsf;              // 131072
  float* kh = qh + 131072;      // 131072
  float* vh = kh + 131072;      // 131072
  float* qpr = vh + 131072;     // 524288
  float* qdr = qpr + 524288;    // 524288
  float* fcT = qdr + 524288;    // 65536   (total ~6.03 MB)

  k_transpose<<<64, 256, 0, stream>>>(fcw, fcT);
  k_proj<<<96, 256, 0, stream>>>(q, k, v, Wq, Bq, Wk, Bk, Wv, Bv, qh, kh, vh);
  k_qprdr<<<256, 256, 0, stream>>>(qh, prw, drw, qpr, qdr);
  k_qk<<<128, 256, 0, stream>>>(qh, kh, attn);
  k_fused<<<512, 256, 0, stream>>>(pitch, dur, qpr, qdr, amask, kpm, vh, fcT, fcb, attn, out);
}